// Round 8
// baseline (1712.011 us; speedup 1.0000x reference)
//
#include <hip/hip_runtime.h>

// SpikingMultiHeadAttention — B=2, S=2048, D=1024, H=16, hd=64, fp32 I/O.
// Round 6b (resubmit after GPU-broker timeout): single mega-kernel, 4 phases,
// device-scope spin barriers — eliminates inter-dispatch overhead AND forces
// per-phase counter visibility.
//   - math is bit-identical to r5 (absmax must stay exactly 1.75):
//     spike(scores*scale) == (raw > 0); sign chain in hi/lo bf16, 3 MFMA
//     passes; V/ctx/out path plain bf16 MFMA.
//   - grid 512 = 2 blocks/CU co-resident (LDS 20KB, bounds(256,2)) -> spin
//     barrier is safe; counters zeroed by init kernel every call.
// MFMA 16x16x32 bf16 layouts (HW-verified):
//   A-frag: lane holds A[m=lane&15][k=(lane>>4)*8+j], j=0..7
//   B-frag: lane holds Bt[n=lane&15][k=(lane>>4)*8+j]
//   C/D:    lane,reg r -> row m=(lane>>4)*4+r, col n=lane&15

#define SEQ 2048
#define DIM 1024
#define NH 16
#define HD 64
#define BATCH 2
#define MROWS (BATCH * SEQ)   // 4096
#define NBLK 512

typedef __attribute__((ext_vector_type(8))) short short8;
typedef __attribute__((ext_vector_type(4))) float f4;
typedef unsigned short ushort;

__device__ __forceinline__ f4 mfma16(short8 a, short8 b, f4 c) {
    return __builtin_amdgcn_mfma_f32_16x16x32_bf16(a, b, c, 0, 0, 0);
}
__device__ __forceinline__ ushort rne16(float x) {
    union { float f; unsigned u; } a; a.f = x;
    return (ushort)((a.u + 0x7fffu + ((a.u >> 16) & 1u)) >> 16);
}
__device__ __forceinline__ void split2(float x, ushort& h, ushort& l) {
    union { float f; unsigned u; } a; a.f = x;
    unsigned hu = a.u & 0xffff0000u;
    h = (ushort)(hu >> 16);
    union { unsigned u; float f; } hb; hb.u = hu;
    l = rne16(x - hb.f);
}
__device__ __forceinline__ short8 ld8(const ushort* p) { return *(const short8*)p; }

// ---- device-scope grid barrier (all NBLK blocks co-resident by construction)
__device__ __forceinline__ void gbar(unsigned* c) {
    __builtin_amdgcn_fence(__ATOMIC_RELEASE, "agent");
    __syncthreads();
    if (threadIdx.x == 0) {
        __hip_atomic_fetch_add(c, 1u, __ATOMIC_ACQ_REL, __HIP_MEMORY_SCOPE_AGENT);
        while (__hip_atomic_load(c, __ATOMIC_ACQUIRE, __HIP_MEMORY_SCOPE_AGENT) < NBLK) {
            __builtin_amdgcn_s_sleep(2);
        }
    }
    __syncthreads();
    __builtin_amdgcn_fence(__ATOMIC_ACQUIRE, "agent");
}

__global__ void init_barriers(unsigned* bar) {
    if (threadIdx.x < 8) bar[threadIdx.x] = 0;
}

// ---------- phase helpers (verbatim r5 math) ----------
template <int B>
__device__ __forceinline__ void ld_qk(const float* __restrict__ X, const ushort* __restrict__ Wh,
                                      const ushort* __restrict__ Wl, int m0, int n0, int la, int qd,
                                      int k0, float4 (&xA)[2][2][2], short8 (&wH)[2][4],
                                      short8 (&wL)[2][4]) {
#pragma unroll
    for (int ms = 0; ms < 2; ++ms) {
        const float* ap = &X[(size_t)(m0 + ms * 16 + la) * DIM + k0 + qd * 8];
        xA[B][ms][0] = *(const float4*)ap;
        xA[B][ms][1] = *(const float4*)(ap + 4);
    }
#pragma unroll
    for (int ns = 0; ns < 4; ++ns) {
        size_t wi = (size_t)(n0 + ns * 16 + la) * DIM + k0 + qd * 8;
        wH[B][ns] = ld8(&Wh[wi]);
        wL[B][ns] = ld8(&Wl[wi]);
    }
}

template <int B>
__device__ __forceinline__ void fma_qk(float4 (&xA)[2][2][2], short8 (&wH)[2][4],
                                       short8 (&wL)[2][4], f4 (&acc)[2][4]) {
    short8 ahi[2], alo[2];
#pragma unroll
    for (int ms = 0; ms < 2; ++ms) {
        float xs[8] = {xA[B][ms][0].x, xA[B][ms][0].y, xA[B][ms][0].z, xA[B][ms][0].w,
                       xA[B][ms][1].x, xA[B][ms][1].y, xA[B][ms][1].z, xA[B][ms][1].w};
#pragma unroll
        for (int j = 0; j < 8; ++j) {
            ushort h, l;
            split2(xs[j], h, l);
            ahi[ms][j] = (short)h;
            alo[ms][j] = (short)l;
        }
    }
#pragma unroll
    for (int ns = 0; ns < 4; ++ns)
#pragma unroll
        for (int ms = 0; ms < 2; ++ms) {
            acc[ms][ns] = mfma16(alo[ms], wH[B][ns], acc[ms][ns]);
            acc[ms][ns] = mfma16(ahi[ms], wL[B][ns], acc[ms][ns]);
            acc[ms][ns] = mfma16(ahi[ms], wH[B][ns], acc[ms][ns]);
        }
}

template <int B>
__device__ __forceinline__ void ld_v(const float* __restrict__ X, const ushort* __restrict__ Wb,
                                     int m0, int n0, int la, int qd, int k0,
                                     float4 (&xA)[2][2][2], short8 (&wH)[2][4]) {
#pragma unroll
    for (int ms = 0; ms < 2; ++ms) {
        const float* ap = &X[(size_t)(m0 + ms * 16 + la) * DIM + k0 + qd * 8];
        xA[B][ms][0] = *(const float4*)ap;
        xA[B][ms][1] = *(const float4*)(ap + 4);
    }
#pragma unroll
    for (int ns = 0; ns < 4; ++ns)
        wH[B][ns] = ld8(&Wb[(size_t)(n0 + ns * 16 + la) * DIM + k0 + qd * 8]);
}

template <int B>
__device__ __forceinline__ void fma_v(float4 (&xA)[2][2][2], short8 (&wH)[2][4], f4 (&acc)[2][4]) {
    short8 a[2];
#pragma unroll
    for (int ms = 0; ms < 2; ++ms) {
        float xs[8] = {xA[B][ms][0].x, xA[B][ms][0].y, xA[B][ms][0].z, xA[B][ms][0].w,
                       xA[B][ms][1].x, xA[B][ms][1].y, xA[B][ms][1].z, xA[B][ms][1].w};
#pragma unroll
        for (int j = 0; j < 8; ++j) a[ms][j] = (short)rne16(xs[j]);
    }
#pragma unroll
    for (int ns = 0; ns < 4; ++ns)
#pragma unroll
        for (int ms = 0; ms < 2; ++ms) acc[ms][ns] = mfma16(a[ms], wH[B][ns], acc[ms][ns]);
}

template <int B>
__device__ __forceinline__ void ld_at(const ushort* __restrict__ Khi, const ushort* __restrict__ Klo,
                                      const ushort* __restrict__ Vt, int bh, int c0, int la, int qd,
                                      short8 (&kH)[2][2][2], short8 (&kL)[2][2][2],
                                      short8 (&vB)[2][4]) {
#pragma unroll
    for (int n2 = 0; n2 < 2; ++n2)
#pragma unroll
        for (int ks = 0; ks < 2; ++ks) {
            size_t ki = ((size_t)bh * SEQ + c0 + n2 * 16 + la) * HD + ks * 32 + qd * 8;
            kH[B][n2][ks] = ld8(&Khi[ki]);
            kL[B][n2][ks] = ld8(&Klo[ki]);
        }
#pragma unroll
    for (int ns = 0; ns < 4; ++ns)
        vB[B][ns] = ld8(&Vt[((size_t)bh * HD + ns * 16 + la) * SEQ + c0 + qd * 8]);
}

template <int B>
__device__ __forceinline__ void half_at(ushort (*Ps)[40], float* __restrict__ attn,
                                        int bh, int q0, int c0, int wave, int lane, int la, int qd,
                                        short8 (&qhi)[2][2], short8 (&qlo)[2][2],
                                        short8 (&kH)[2][2][2], short8 (&kL)[2][2][2],
                                        short8 (&vB)[2][4], f4 (&cacc)[2][4]) {
    f4 s[2][2] = {};
#pragma unroll
    for (int n2 = 0; n2 < 2; ++n2)
#pragma unroll
        for (int ks = 0; ks < 2; ++ks)
#pragma unroll
            for (int ms = 0; ms < 2; ++ms) {
                s[ms][n2] = mfma16(qlo[ms][ks], kH[B][n2][ks], s[ms][n2]);
                s[ms][n2] = mfma16(qhi[ms][ks], kL[B][n2][ks], s[ms][n2]);
                s[ms][n2] = mfma16(qhi[ms][ks], kH[B][n2][ks], s[ms][n2]);
            }
#pragma unroll
    for (int ms = 0; ms < 2; ++ms)
#pragma unroll
        for (int n2 = 0; n2 < 2; ++n2)
#pragma unroll
            for (int r = 0; r < 4; ++r)
                Ps[wave * 32 + ms * 16 + qd * 4 + r][n2 * 16 + la] =
                    s[ms][n2][r] > 0.f ? (ushort)0x3f80 : (ushort)0;
#pragma unroll
    for (int it = 0; it < 4; ++it) {
        int row = it * 8 + (lane >> 3);
        short4 p = *(const short4*)&Ps[wave * 32 + row][(lane & 7) * 4];
        float4 o;
        o.x = __uint_as_float(((unsigned)(ushort)p.x) << 16);
        o.y = __uint_as_float(((unsigned)(ushort)p.y) << 16);
        o.z = __uint_as_float(((unsigned)(ushort)p.z) << 16);
        o.w = __uint_as_float(((unsigned)(ushort)p.w) << 16);
        *(float4*)&attn[((size_t)bh * SEQ + q0 + row) * SEQ + c0 + (lane & 7) * 4] = o;
    }
    short8 pa[2];
#pragma unroll
    for (int ms = 0; ms < 2; ++ms)
        pa[ms] = *(const short8*)&Ps[wave * 32 + ms * 16 + la][qd * 8];
#pragma unroll
    for (int ns = 0; ns < 4; ++ns)
#pragma unroll
        for (int ms = 0; ms < 2; ++ms) cacc[ms][ns] = mfma16(pa[ms], vB[B][ns], cacc[ms][ns]);
}

template <int B>
__device__ __forceinline__ void ld_o(const ushort* __restrict__ Ctx, const ushort* __restrict__ Wb,
                                     int m0, int n0, int la, int qd, int k0,
                                     short8 (&aO)[2][2], short8 (&wO)[2][4]) {
#pragma unroll
    for (int ms = 0; ms < 2; ++ms) {
        int m = m0 + ms * 16 + la;
        int b = m >> 11, s = m & 2047;
        int k = k0 + qd * 8;
        int h = k >> 6, d = k & 63;
        aO[B][ms] = ld8(&Ctx[((size_t)(b * NH + h) * SEQ + s) * HD + d]);
    }
#pragma unroll
    for (int ns = 0; ns < 4; ++ns)
        wO[B][ns] = ld8(&Wb[(size_t)(n0 + ns * 16 + la) * DIM + k0 + qd * 8]);
}

// ---------- the mega kernel ----------
__global__ __launch_bounds__(256, 2) void mega(
    const float* __restrict__ query, const float* __restrict__ key, const float* __restrict__ value,
    const float* __restrict__ Wq, const float* __restrict__ bq,
    const float* __restrict__ Wk, const float* __restrict__ bk,
    const float* __restrict__ Wv, const float* __restrict__ bv,
    const float* __restrict__ Wo, const float* __restrict__ bo,
    float* __restrict__ out, float* __restrict__ attn,
    ushort* __restrict__ Qhi, ushort* __restrict__ Qlo,
    ushort* __restrict__ Khi, ushort* __restrict__ Klo,
    ushort* __restrict__ Vt, ushort* __restrict__ Ctx,
    ushort* __restrict__ Wqh, ushort* __restrict__ Wql,
    ushort* __restrict__ Wkh, ushort* __restrict__ Wkl,
    ushort* __restrict__ Wvb, ushort* __restrict__ Wob,
    unsigned* __restrict__ bar) {
    __shared__ ushort smem[10240];  // 20 KB: Ts[4][64][40] | Ps[128][40]
    const int t = threadIdx.x, wave = t >> 6, lane = t & 63;
    const int la = lane & 15, qd = lane >> 4;
    const int bid = blockIdx.x;

    // ---- phase W: weight conversion (4 x 1M elems over 512 blocks) ----
    {
#pragma unroll
        for (int u = 0; u < 8; ++u) {
            int unit = bid * 8 + u;             // 0..4095
            int mat = unit >> 10;               // 0..3
            int i = (unit & 1023) * 1024 + t * 4;
            const float* src = mat == 0 ? Wq : mat == 1 ? Wk : mat == 2 ? Wv : Wo;
            float4 w = *(const float4*)&src[i];
            float xs[4] = {w.x, w.y, w.z, w.w};
            if (mat < 2) {
                ushort h[4], l[4];
#pragma unroll
                for (int j = 0; j < 4; ++j) split2(xs[j], h[j], l[j]);
                ushort* ph = mat ? Wkh : Wqh;
                ushort* pl = mat ? Wkl : Wql;
                *(short4*)&ph[i] = make_short4(h[0], h[1], h[2], h[3]);
                *(short4*)&pl[i] = make_short4(l[0], l[1], l[2], l[3]);
            } else {
                ushort* po = mat == 2 ? Wvb : Wob;
                *(short4*)&po[i] = make_short4(rne16(xs[0]), rne16(xs[1]), rne16(xs[2]), rne16(xs[3]));
            }
        }
    }
    gbar(bar + 0);

    // ---- phase QKV: 3 jobs per block over (32 m-blocks x 16 n-blocks) ----
    {
        const int xb = bid & 31, yb = bid >> 5;
        const int m0 = xb * 128 + wave * 32;
        const int n0 = yb * 64;
        float4 xA[2][2][2];
        short8 wH[2][4], wL[2][4];
#pragma unroll
        for (int z = 0; z < 2; ++z) {
            const float* X = z ? key : query;
            const ushort* Wh = z ? Wkh : Wqh;
            const ushort* Wl = z ? Wkl : Wql;
            f4 acc[2][4] = {};
            ld_qk<0>(X, Wh, Wl, m0, n0, la, qd, 0, xA, wH, wL);
            for (int k0 = 0; k0 < DIM; k0 += 64) {
                ld_qk<1>(X, Wh, Wl, m0, n0, la, qd, k0 + 32, xA, wH, wL);
                fma_qk<0>(xA, wH, wL, acc);
                ld_qk<0>(X, Wh, Wl, m0, n0, la, qd, (k0 + 64) & (DIM - 1), xA, wH, wL);
                fma_qk<1>(xA, wH, wL, acc);
            }
            const float* bias = z ? bk : bq;
            ushort* Oh = z ? Khi : Qhi;
            ushort* Ol = z ? Klo : Qlo;
#pragma unroll
            for (int ns = 0; ns < 4; ++ns) {
                int n = n0 + ns * 16 + la;
                float bvv = bias[n];
                int h = n >> 6, d = n & 63;
#pragma unroll
                for (int ms = 0; ms < 2; ++ms)
#pragma unroll
                    for (int r = 0; r < 4; ++r) {
                        int m = m0 + ms * 16 + qd * 4 + r;
                        int b = m >> 11, s = m & 2047;
                        ushort hh, ll;
                        split2(acc[ms][ns][r] + bvv, hh, ll);
                        size_t o = ((size_t)(b * NH + h) * SEQ + s) * HD + d;
                        Oh[o] = hh;
                        Ol[o] = ll;
                    }
            }
        }
        {   // v path
            ushort(*Ts)[64][40] = (ushort(*)[64][40])smem;
            f4 acc[2][4] = {};
            ld_v<0>(value, Wvb, m0, n0, la, qd, 0, xA, wH);
            for (int k0 = 0; k0 < DIM; k0 += 64) {
                ld_v<1>(value, Wvb, m0, n0, la, qd, k0 + 32, xA, wH);
                fma_v<0>(xA, wH, acc);
                ld_v<0>(value, Wvb, m0, n0, la, qd, (k0 + 64) & (DIM - 1), xA, wH);
                fma_v<1>(xA, wH, acc);
            }
#pragma unroll
            for (int ns = 0; ns < 4; ++ns) {
                float bvv = bv[n0 + ns * 16 + la];
#pragma unroll
                for (int ms = 0; ms < 2; ++ms)
#pragma unroll
                    for (int r = 0; r < 4; ++r)
                        Ts[wave][ns * 16 + la][ms * 16 + qd * 4 + r] = rne16(acc[ms][ns][r] + bvv);
            }
            int b = m0 >> 11, s0 = m0 & 2047, h = n0 >> 6;
            size_t vbase = (size_t)(b * NH + h) * HD * SEQ;
#pragma unroll
            for (int it = 0; it < 4; ++it) {
                int d = it * 16 + (lane >> 2), sc = (lane & 3) * 8;
                short8 v0 = *(const short8*)&Ts[wave][d][sc];
                *(short8*)&Vt[vbase + (size_t)d * SEQ + s0 + sc] = v0;
            }
        }
    }
    gbar(bar + 1);

    // ---- phase ATTN: 1 job per block: bh = bid&31, q-block = bid>>5 ----
    {
        ushort(*Ps)[40] = (ushort(*)[40])smem;
        const int bh = bid & 31;
        const int q0 = (bid >> 5) * 128 + wave * 32;
        short8 qhi[2][2], qlo[2][2];
#pragma unroll
        for (int ms = 0; ms < 2; ++ms)
#pragma unroll
            for (int ks = 0; ks < 2; ++ks) {
                size_t qi = ((size_t)bh * SEQ + q0 + ms * 16 + la) * HD + ks * 32 + qd * 8;
                qhi[ms][ks] = ld8(&Qhi[qi]);
                qlo[ms][ks] = ld8(&Qlo[qi]);
            }
        short8 kH[2][2][2], kL[2][2][2], vB[2][4];
        f4 cacc[2][4] = {};
        ld_at<0>(Khi, Klo, Vt, bh, 0, la, qd, kH, kL, vB);
        for (int h = 0; h < 64; h += 2) {
            ld_at<1>(Khi, Klo, Vt, bh, (h + 1) * 32, la, qd, kH, kL, vB);
            half_at<0>(Ps, attn, bh, q0, h * 32, wave, lane, la, qd, qhi, qlo, kH, kL, vB, cacc);
            ld_at<0>(Khi, Klo, Vt, bh, ((h + 2) & 63) * 32, la, qd, kH, kL, vB);
            half_at<1>(Ps, attn, bh, q0, (h + 1) * 32, wave, lane, la, qd, qhi, qlo, kH, kL, vB, cacc);
        }
#pragma unroll
        for (int ns = 0; ns < 4; ++ns)
#pragma unroll
            for (int ms = 0; ms < 2; ++ms)
#pragma unroll
                for (int r = 0; r < 4; ++r) {
                    int qrow = q0 + ms * 16 + qd * 4 + r;
                    Ctx[((size_t)bh * SEQ + qrow) * HD + ns * 16 + la] = rne16(cacc[ms][ns][r]);
                }
    }
    gbar(bar + 2);

    // ---- phase OUT: 1 job per block: m-blk = bid&31, n-blk = bid>>5 ----
    {
        const int m0 = (bid & 31) * 128 + wave * 32;
        const int n0 = (bid >> 5) * 64;
        short8 aO[2][2], wO[2][4];
        f4 acc[2][4] = {};
        ld_o<0>(Ctx, Wob, m0, n0, la, qd, 0, aO, wO);
        for (int k0 = 0; k0 < DIM; k0 += 64) {
            ld_o<1>(Ctx, Wob, m0, n0, la, qd, k0 + 32, aO, wO);
#pragma unroll
            for (int ns = 0; ns < 4; ++ns)
#pragma unroll
                for (int ms = 0; ms < 2; ++ms) acc[ms][ns] = mfma16(aO[0][ms], wO[0][ns], acc[ms][ns]);
            ld_o<0>(Ctx, Wob, m0, n0, la, qd, (k0 + 64) & (DIM - 1), aO, wO);
#pragma unroll
            for (int ns = 0; ns < 4; ++ns)
#pragma unroll
                for (int ms = 0; ms < 2; ++ms) acc[ms][ns] = mfma16(aO[1][ms], wO[1][ns], acc[ms][ns]);
        }
#pragma unroll
        for (int ns = 0; ns < 4; ++ns) {
            int n = n0 + ns * 16 + la;
            float bvv = bo[n];
#pragma unroll
            for (int ms = 0; ms < 2; ++ms)
#pragma unroll
                for (int r = 0; r < 4; ++r) {
                    int m = m0 + ms * 16 + qd * 4 + r;
                    out[(size_t)m * DIM + n] = acc[ms][ns][r] + bvv;
                }
        }
    }
}

extern "C" void kernel_launch(void* const* d_in, const int* in_sizes, int n_in,
                              void* d_out, int out_size, void* d_ws, size_t ws_size,
                              hipStream_t stream) {
    const float* query = (const float*)d_in[0];
    const float* key   = (const float*)d_in[1];
    const float* value = (const float*)d_in[2];
    const float* Wq = (const float*)d_in[3];
    const float* bq = (const float*)d_in[4];
    const float* Wk = (const float*)d_in[5];
    const float* bk = (const float*)d_in[6];
    const float* Wv = (const float*)d_in[7];
    const float* bv = (const float*)d_in[8];
    const float* Wo = (const float*)d_in[9];
    const float* bo = (const float*)d_in[10];

    float* out  = (float*)d_out;
    float* attn = out + (size_t)MROWS * DIM;

    const size_t NE = (size_t)MROWS * DIM;  // 4,194,304
    const size_t WE = (size_t)DIM * DIM;    // 1,048,576
    ushort* Qhi = (ushort*)d_ws;            // 5 x NE = 40 MiB
    ushort* Qlo = Qhi + NE;
    ushort* Khi = Qlo + NE;
    ushort* Klo = Khi + NE;
    ushort* Vt  = Klo + NE;
    ushort* Wqh = Vt + NE;                  // 6 x WE = 12 MiB
    ushort* Wql = Wqh + WE;
    ushort* Wkh = Wql + WE;
    ushort* Wkl = Wkh + WE;
    ushort* Wvb = Wkl + WE;
    ushort* Wob = Wvb + WE;
    ushort* Ctx = Wqh;                      // overlays Wqh..Wkl (dead after phase QKV)
    unsigned* bar = (unsigned*)(Wob + WE);  // 8 x u32 barrier counters

    hipLaunchKernelGGL(init_barriers, dim3(1), dim3(64), 0, stream, bar);
    hipLaunchKernelGGL(mega, dim3(NBLK), dim3(256), 0, stream,
                       query, key, value, Wq, bq, Wk, bk, Wv, bv, Wo, bo,
                       out, attn, Qhi, Qlo, Khi, Klo, Vt, Ctx,
                       Wqh, Wql, Wkh, Wkl, Wvb, Wob, bar);
}